// Round 1
// baseline (3491.853 us; speedup 1.0000x reference)
//
#include <hip/hip_runtime.h>
#include <hip/hip_bf16.h>

// Problem constants
#define S_TOT 5184      // total sequence
#define T_TXT 64        // text tokens
#define OFF0  64        // start of image0 (32x32)
#define OFF1  1088      // start of image1 (64x64)
#define NHEAD 16
#define CH    64        // channels per head
#define HID   1024
#define BATCH 4
#define BN_TOT (BATCH*NHEAD)   // 64

// ---------------- helpers ----------------
__device__ __forceinline__ float dot64(const float4* __restrict__ q, const float* __restrict__ kp) {
  const float4* k4 = (const float4*)kp;
  float s = 0.f;
#pragma unroll
  for (int i = 0; i < 16; ++i) {
    float4 a = q[i]; float4 b = k4[i];
    s = fmaf(a.x, b.x, s); s = fmaf(a.y, b.y, s);
    s = fmaf(a.z, b.z, s); s = fmaf(a.w, b.w, s);
  }
  return s;
}

__device__ __forceinline__ void fma64(float4* __restrict__ acc, float w, const float* __restrict__ vp) {
  const float4* v4 = (const float4*)vp;
#pragma unroll
  for (int i = 0; i < 16; ++i) {
    float4 v = v4[i];
    acc[i].x = fmaf(w, v.x, acc[i].x);
    acc[i].y = fmaf(w, v.y, acc[i].y);
    acc[i].z = fmaf(w, v.z, acc[i].z);
    acc[i].w = fmaf(w, v.w, acc[i].w);
  }
}

// ---------------- f32 tiled GEMM: C = A(MxK) * B(KxN) + bias ----------------
// EPI==0: plain store to C.  EPI==1: scatter into q/k/v buffers [bh][s][64] (q scaled by 0.125).
template<int EPI>
__global__ __launch_bounds__(256) void gemm128(
    const float* __restrict__ A, const float* __restrict__ Bm,
    const float* __restrict__ bias, float* __restrict__ C,
    float* __restrict__ qbuf, float* __restrict__ kbuf, float* __restrict__ vbuf,
    const int M, const int N, const int K)
{
  __shared__ __align__(16) float As[16][132];
  __shared__ __align__(16) float Bs[16][132];
  const int tid = threadIdx.x;
  const int bm = blockIdx.x * 128;
  const int bn = blockIdx.y * 128;
  const int tx = tid & 15, ty = tid >> 4;

  float acc[2][2][4][4];
#pragma unroll
  for (int a = 0; a < 2; ++a)
#pragma unroll
    for (int b = 0; b < 2; ++b)
#pragma unroll
      for (int i = 0; i < 4; ++i)
#pragma unroll
        for (int j = 0; j < 4; ++j) acc[a][b][i][j] = 0.f;

  for (int k0 = 0; k0 < K; k0 += 16) {
#pragma unroll
    for (int l = 0; l < 2; ++l) {
      const int idx  = tid + l * 256;
      // A tile: 128 rows x 16 cols, store transposed As[k][m]
      const int arow = idx >> 2;
      const int ac4  = (idx & 3) << 2;
      const float4 av = *(const float4*)(A + (size_t)(bm + arow) * K + k0 + ac4);
      As[ac4 + 0][arow] = av.x; As[ac4 + 1][arow] = av.y;
      As[ac4 + 2][arow] = av.z; As[ac4 + 3][arow] = av.w;
      // B tile: 16 rows x 128 cols
      const int brow = idx >> 5;
      const int bc4  = (idx & 31) << 2;
      *(float4*)(&Bs[brow][bc4]) = *(const float4*)(Bm + (size_t)(k0 + brow) * N + bn + bc4);
    }
    __syncthreads();
#pragma unroll
    for (int k = 0; k < 16; ++k) {
      float a[2][4], b[2][4];
      *(float4*)(a[0]) = *(const float4*)(&As[k][ty * 4]);
      *(float4*)(a[1]) = *(const float4*)(&As[k][64 + ty * 4]);
      *(float4*)(b[0]) = *(const float4*)(&Bs[k][tx * 4]);
      *(float4*)(b[1]) = *(const float4*)(&Bs[k][64 + tx * 4]);
#pragma unroll
      for (int rh = 0; rh < 2; ++rh)
#pragma unroll
        for (int ch = 0; ch < 2; ++ch)
#pragma unroll
          for (int i = 0; i < 4; ++i)
#pragma unroll
            for (int j = 0; j < 4; ++j)
              acc[rh][ch][i][j] = fmaf(a[rh][i], b[ch][j], acc[rh][ch][i][j]);
    }
    __syncthreads();
  }

  // epilogue
#pragma unroll
  for (int rh = 0; rh < 2; ++rh)
#pragma unroll
    for (int i = 0; i < 4; ++i) {
      const int row = bm + rh * 64 + ty * 4 + i;
#pragma unroll
      for (int ch = 0; ch < 2; ++ch) {
        const int col = bn + ch * 64 + tx * 4;
        float4 r;
        r.x = acc[rh][ch][i][0] + bias[col + 0];
        r.y = acc[rh][ch][i][1] + bias[col + 1];
        r.z = acc[rh][ch][i][2] + bias[col + 2];
        r.w = acc[rh][ch][i][3] + bias[col + 3];
        if constexpr (EPI == 0) {
          *(float4*)(&C[(size_t)row * N + col]) = r;
        } else {
          const int b_   = row / S_TOT;
          const int s_   = row - b_ * S_TOT;
          const int type = col >> 10;           // 0=q 1=k 2=v
          const int head = (col & 1023) >> 6;
          const int chn  = col & 63;            // == tx*4
          float* dst = (type == 0) ? qbuf : ((type == 1) ? kbuf : vbuf);
          if (type == 0) { r.x *= 0.125f; r.y *= 0.125f; r.z *= 0.125f; r.w *= 0.125f; }
          *(float4*)(&dst[(((size_t)(b_ * NHEAD + head)) * S_TOT + s_) * CH + chn]) = r;
        }
      }
    }
}

// ---------------- attention: text queries (s in [0,64)) ----------------
__global__ __launch_bounds__(64) void attn_text(
    const float* __restrict__ qb, const float* __restrict__ kb, const float* __restrict__ vb,
    const float* __restrict__ mask, float* __restrict__ ctx)
{
  __shared__ float smem[64][65];
  const int bh = blockIdx.x;
  const int b_ = bh >> 4, head = bh & 15;
  const int tq = threadIdx.x;       // query position 0..63

  float4 q[16];
  const float4* qp = (const float4*)(qb + ((size_t)bh * S_TOT + tq) * CH);
#pragma unroll
  for (int i = 0; i < 16; ++i) q[i] = qp[i];

  float* sc = smem[tq];
  const float* mrow = mask + ((size_t)b_ * S_TOT + tq) * T_TXT;
  const float* kt = kb + (size_t)bh * S_TOT * CH;
  float mx = -1e30f;
  for (int j = 0; j < T_TXT; ++j) {
    float d = dot64(q, kt + j * CH);
    float m = mrow[j];
    d = d * m - 10000.f * (1.f - m);
    sc[j] = d; mx = fmaxf(mx, d);
  }
  float l = 0.f;
  for (int j = 0; j < T_TXT; ++j) { float e = __expf(sc[j] - mx); sc[j] = e; l += e; }
  const float inv = 1.f / l;

  float4 acc[16];
#pragma unroll
  for (int i = 0; i < 16; ++i) acc[i] = make_float4(0.f, 0.f, 0.f, 0.f);
  const float* vt = vb + (size_t)bh * S_TOT * CH;
  for (int j = 0; j < T_TXT; ++j) fma64(acc, sc[j] * inv, vt + j * CH);

  float4* cp = (float4*)(ctx + ((size_t)(b_ * S_TOT + tq)) * HID + head * CH);
#pragma unroll
  for (int i = 0; i < 16; ++i) cp[i] = acc[i];
}

// ---------------- attention: image0 queries (32x32, 9x9 causal) ----------------
__global__ __launch_bounds__(64) void attn_img0(
    const float* __restrict__ qb, const float* __restrict__ kb, const float* __restrict__ vb,
    const float* __restrict__ mask, float* __restrict__ ctx)
{
  __shared__ float smem[64][109];   // 105 scores, padded (109%32=13, coprime w/ 32)
  const int bid = blockIdx.x;       // 0..1023
  const int bh = bid >> 4;
  const int p = (bid & 15) * 64 + threadIdx.x;   // 0..1023
  const int qi = p >> 5, qj = p & 31;
  const int s = OFF0 + p;
  const int b_ = bh >> 4, head = bh & 15;

  float4 q[16];
  const float4* qp = (const float4*)(qb + ((size_t)bh * S_TOT + s) * CH);
#pragma unroll
  for (int i = 0; i < 16; ++i) q[i] = qp[i];

  float* sc = smem[threadIdx.x];
  const float* mrow = mask + ((size_t)b_ * S_TOT + s) * T_TXT;
  const float* kt = kb + (size_t)bh * S_TOT * CH;
  float mx = -1e30f;
  for (int j = 0; j < T_TXT; ++j) {
    float d = dot64(q, kt + j * CH);
    float m = mrow[j];
    d = d * m - 10000.f * (1.f - m);
    sc[j] = d; mx = fmaxf(mx, d);
  }
  // 41 causal 9x9 offsets within 32x32 grid (k0)
  const float* k0 = kb + ((size_t)bh * S_TOT + OFF0) * CH;
  for (int o = 0; o < 41; ++o) {
    const int di = o / 9 - 4, dj = o % 9 - 4;
    const int ki = qi + di, kj = qj + dj;
    float d = 0.f;
    if ((unsigned)ki < 32u && (unsigned)kj < 32u)
      d = dot64(q, k0 + (ki * 32 + kj) * CH);
    sc[64 + o] = d; mx = fmaxf(mx, d);
  }
  float l = 0.f;
  for (int j = 0; j < 105; ++j) { float e = __expf(sc[j] - mx); sc[j] = e; l += e; }
  const float inv = 1.f / l;

  float4 acc[16];
#pragma unroll
  for (int i = 0; i < 16; ++i) acc[i] = make_float4(0.f, 0.f, 0.f, 0.f);
  const float* vt = vb + (size_t)bh * S_TOT * CH;
  for (int j = 0; j < T_TXT; ++j) fma64(acc, sc[j] * inv, vt + j * CH);
  const float* v0 = vb + ((size_t)bh * S_TOT + OFF0) * CH;
  for (int o = 0; o < 41; ++o) {
    const int di = o / 9 - 4, dj = o % 9 - 4;
    const int ki = qi + di, kj = qj + dj;
    if ((unsigned)ki < 32u && (unsigned)kj < 32u)
      fma64(acc, sc[64 + o] * inv, v0 + (ki * 32 + kj) * CH);
  }
  float4* cp = (float4*)(ctx + ((size_t)(b_ * S_TOT + s)) * HID + head * CH);
#pragma unroll
  for (int i = 0; i < 16; ++i) cp[i] = acc[i];
}

// ---------------- attention: image1 queries (64x64; 7x7 over k0 + 9x9 causal over k1) ----------------
__global__ __launch_bounds__(64) void attn_img1(
    const float* __restrict__ qb, const float* __restrict__ kb, const float* __restrict__ vb,
    const float* __restrict__ mask, float* __restrict__ ctx)
{
  __shared__ float smem[64][157];   // 154 scores, padded (157%32=29, coprime w/ 32)
  const int bid = blockIdx.x;       // 0..4095
  const int bh = bid >> 6;
  const int p = (bid & 63) * 64 + threadIdx.x;   // 0..4095
  const int qi = p >> 6, qj = p & 63;
  const int s = OFF1 + p;
  const int b_ = bh >> 4, head = bh & 15;

  float4 q[16];
  const float4* qp = (const float4*)(qb + ((size_t)bh * S_TOT + s) * CH);
#pragma unroll
  for (int i = 0; i < 16; ++i) q[i] = qp[i];

  float* sc = smem[threadIdx.x];
  const float* mrow = mask + ((size_t)b_ * S_TOT + s) * T_TXT;
  const float* kt = kb + (size_t)bh * S_TOT * CH;
  float mx = -1e30f;
  for (int j = 0; j < T_TXT; ++j) {
    float d = dot64(q, kt + j * CH);
    float m = mrow[j];
    d = d * m - 10000.f * (1.f - m);
    sc[j] = d; mx = fmaxf(mx, d);
  }
  // 49 full 7x7 offsets: query (qi,qj) -> base (qi/2, qj/2) in 32x32 grid (k0)
  const float* k0 = kb + ((size_t)bh * S_TOT + OFF0) * CH;
  const int ki0 = qi >> 1, kj0 = qj >> 1;
  for (int o = 0; o < 49; ++o) {
    const int ki = ki0 + o / 7 - 3, kj = kj0 + o % 7 - 3;
    float d = 0.f;
    if ((unsigned)ki < 32u && (unsigned)kj < 32u)
      d = dot64(q, k0 + (ki * 32 + kj) * CH);
    sc[64 + o] = d; mx = fmaxf(mx, d);
  }
  // 41 causal 9x9 offsets within 64x64 grid (k1)
  const float* k1 = kb + ((size_t)bh * S_TOT + OFF1) * CH;
  for (int o = 0; o < 41; ++o) {
    const int ki = qi + o / 9 - 4, kj = qj + o % 9 - 4;
    float d = 0.f;
    if ((unsigned)ki < 64u && (unsigned)kj < 64u)
      d = dot64(q, k1 + (ki * 64 + kj) * CH);
    sc[113 + o] = d; mx = fmaxf(mx, d);
  }
  float l = 0.f;
  for (int j = 0; j < 154; ++j) { float e = __expf(sc[j] - mx); sc[j] = e; l += e; }
  const float inv = 1.f / l;

  float4 acc[16];
#pragma unroll
  for (int i = 0; i < 16; ++i) acc[i] = make_float4(0.f, 0.f, 0.f, 0.f);
  const float* vt = vb + (size_t)bh * S_TOT * CH;
  for (int j = 0; j < T_TXT; ++j) fma64(acc, sc[j] * inv, vt + j * CH);
  const float* v0 = vb + ((size_t)bh * S_TOT + OFF0) * CH;
  for (int o = 0; o < 49; ++o) {
    const int ki = ki0 + o / 7 - 3, kj = kj0 + o % 7 - 3;
    if ((unsigned)ki < 32u && (unsigned)kj < 32u)
      fma64(acc, sc[64 + o] * inv, v0 + (ki * 32 + kj) * CH);
  }
  const float* v1 = vb + ((size_t)bh * S_TOT + OFF1) * CH;
  for (int o = 0; o < 41; ++o) {
    const int ki = qi + o / 9 - 4, kj = qj + o % 9 - 4;
    if ((unsigned)ki < 64u && (unsigned)kj < 64u)
      fma64(acc, sc[113 + o] * inv, v1 + (ki * 64 + kj) * CH);
  }
  float4* cp = (float4*)(ctx + ((size_t)(b_ * S_TOT + s)) * HID + head * CH);
#pragma unroll
  for (int i = 0; i < 16; ++i) cp[i] = acc[i];
}

// ---------------- launch ----------------
extern "C" void kernel_launch(void* const* d_in, const int* in_sizes, int n_in,
                              void* d_out, int out_size, void* d_ws, size_t ws_size,
                              hipStream_t stream) {
  const float* hidden = (const float*)d_in[0];
  const float* mask   = (const float*)d_in[1];
  const float* w_qkv  = (const float*)d_in[2];
  const float* b_qkv  = (const float*)d_in[3];
  const float* w_out  = (const float*)d_in[4];
  const float* b_out  = (const float*)d_in[5];
  float* out = (float*)d_out;
  float* ws  = (float*)d_ws;

  const size_t NB = (size_t)BN_TOT * S_TOT * CH;   // 21,233,664 floats
  float* qbuf = ws;
  float* kbuf = ws + NB;
  float* vbuf = ws + 2 * NB;
  float* ctx  = ws + 3 * NB;

  const int M = BATCH * S_TOT;   // 20736

  // 1) QKV projection with scatter epilogue
  {
    dim3 grid(M / 128, 3072 / 128);
    gemm128<1><<<grid, 256, 0, stream>>>(hidden, w_qkv, b_qkv, nullptr,
                                         qbuf, kbuf, vbuf, M, 3072, 1024);
  }
  // 2) attention
  attn_text<<<BN_TOT, 64, 0, stream>>>(qbuf, kbuf, vbuf, mask, ctx);
  attn_img0<<<BN_TOT * 16, 64, 0, stream>>>(qbuf, kbuf, vbuf, mask, ctx);
  attn_img1<<<BN_TOT * 64, 64, 0, stream>>>(qbuf, kbuf, vbuf, mask, ctx);
  // 3) output projection
  {
    dim3 grid(M / 128, 1024 / 128);
    gemm128<0><<<grid, 256, 0, stream>>>(ctx, w_out, b_out, out,
                                         nullptr, nullptr, nullptr, M, 1024, 1024);
  }
}

// Round 2
// 1664.976 us; speedup vs baseline: 2.0972x; 2.0972x over previous
//
#include <hip/hip_runtime.h>
#include <hip/hip_bf16.h>

// Problem constants
#define S_TOT 5184      // total sequence
#define T_TXT 64        // text tokens
#define OFF0  64        // start of image0 (32x32)
#define OFF1  1088      // start of image1 (64x64)
#define NHEAD 16
#define CH    64        // channels per head
#define HID   1024
#define BATCH 4
#define BN_TOT (BATCH*NHEAD)   // 64

typedef __attribute__((ext_vector_type(8))) short bf16x8;
typedef __attribute__((ext_vector_type(4))) float f32x4;

__device__ __forceinline__ unsigned int f2bf(float x) {
  unsigned int u = __float_as_uint(x);
  unsigned int r = u + 0x7fffu + ((u >> 16) & 1u);
  return r >> 16;   // RNE bf16 in low 16 bits
}

__device__ __forceinline__ void gload_lds16(const short* g, short* l) {
  __builtin_amdgcn_global_load_lds(
      (const __attribute__((address_space(1))) unsigned int*)g,
      (__attribute__((address_space(3))) unsigned int*)l, 16, 0, 0);
}

// ---------------- conversion kernels ----------------
__global__ __launch_bounds__(256) void cvt_bf16(const float* __restrict__ in,
                                                unsigned int* __restrict__ out, int n8) {
  const int i = blockIdx.x * 256 + threadIdx.x;
  if (i >= n8) return;
  const float4 a = ((const float4*)in)[2 * i];
  const float4 b = ((const float4*)in)[2 * i + 1];
  uint4 r;
  r.x = f2bf(a.x) | (f2bf(a.y) << 16);
  r.y = f2bf(a.z) | (f2bf(a.w) << 16);
  r.z = f2bf(b.x) | (f2bf(b.y) << 16);
  r.w = f2bf(b.z) | (f2bf(b.w) << 16);
  ((uint4*)out)[i] = r;
}

// in: f32 [R][Cn] row-major -> out: bf16 [Cn][R]
__global__ void cvt_T(const float* __restrict__ in, short* __restrict__ out,
                      const int R, const int Cn) {
  __shared__ float t[32][33];
  const int bx = blockIdx.x * 32, by = blockIdx.y * 32;
  const int tx = threadIdx.x, ty = threadIdx.y;
#pragma unroll
  for (int ph = 0; ph < 4; ++ph)
    t[ty + ph * 8][tx] = in[(size_t)(by + ty + ph * 8) * Cn + bx + tx];
  __syncthreads();
#pragma unroll
  for (int ph = 0; ph < 4; ++ph)
    out[(size_t)(bx + ty + ph * 8) * R + by + tx] = (short)f2bf(t[tx][ty + ph * 8]);
}

// ---------------- bf16 MFMA GEMM: C = A(MxK) * BT(NxK)^T + bias ----------------
// EPI==0: f32 store to C.  EPI==1: scatter into q/k/v f32 buffers [bh][s][64] (q * 0.125).
template<int EPI>
__global__ __launch_bounds__(256) void gemm_mfma(
    const short* __restrict__ A, const short* __restrict__ BT,
    const float* __restrict__ bias, float* __restrict__ C,
    float* __restrict__ qbuf, float* __restrict__ kbuf, float* __restrict__ vbuf,
    const int M, const int N, const int K)
{
  __shared__ short As[128 * 32];
  __shared__ short Bs[128 * 32];
  const int tid = threadIdx.x;
  const int w = tid >> 6, l = tid & 63;
  const int bm = blockIdx.x * 128, bn = blockIdx.y * 128;
  const int wr = w >> 1, wc = w & 1;
  const int lr = l & 15, lk = (l >> 4) * 8;

  // staging source: wave w stages 32 rows of A-tile / BT-tile; lane l -> row (l>>2), col (l&3)*8
  const short* aSrc = A + (size_t)(bm + w * 32 + (l >> 2)) * K + (l & 3) * 8;
  const short* bSrc = BT + (size_t)(bn + w * 32 + (l >> 2)) * K + (l & 3) * 8;
  short* aDst = As + w * 32 * 32;
  short* bDst = Bs + w * 32 * 32;

  f32x4 acc[4][4];
#pragma unroll
  for (int m = 0; m < 4; ++m)
#pragma unroll
    for (int n = 0; n < 4; ++n) acc[m][n] = (f32x4){0.f, 0.f, 0.f, 0.f};

  for (int k0 = 0; k0 < K; k0 += 32) {
    gload_lds16(aSrc + k0,            aDst);
    gload_lds16(aSrc + k0 + 16 * K,   aDst + 16 * 32);
    gload_lds16(bSrc + k0,            bDst);
    gload_lds16(bSrc + k0 + 16 * K,   bDst + 16 * 32);
    __syncthreads();
    bf16x8 af[4], bfr[4];
#pragma unroll
    for (int m = 0; m < 4; ++m)
      af[m] = *(const bf16x8*)&As[(wr * 64 + m * 16 + lr) * 32 + lk];
#pragma unroll
    for (int n = 0; n < 4; ++n)
      bfr[n] = *(const bf16x8*)&Bs[(wc * 64 + n * 16 + lr) * 32 + lk];
#pragma unroll
    for (int m = 0; m < 4; ++m)
#pragma unroll
      for (int n = 0; n < 4; ++n)
        acc[m][n] = __builtin_amdgcn_mfma_f32_16x16x32_bf16(af[m], bfr[n], acc[m][n], 0, 0, 0);
    __syncthreads();
  }

  // epilogue: C row = (l>>4)*4 + i, col = lr within each 16x16 fragment
#pragma unroll
  for (int m = 0; m < 4; ++m) {
    const int row0 = bm + wr * 64 + m * 16 + (l >> 4) * 4;
#pragma unroll
    for (int n = 0; n < 4; ++n) {
      const int col = bn + wc * 64 + n * 16 + lr;
      const float bv = bias[col];
      if constexpr (EPI == 0) {
#pragma unroll
        for (int i = 0; i < 4; ++i)
          C[(size_t)(row0 + i) * N + col] = acc[m][n][i] + bv;
      } else {
        const int type = col >> 10;            // 0=q 1=k 2=v
        const int head = (col & 1023) >> 6;
        const int chn  = col & 63;
        float* dst = (type == 0) ? qbuf : ((type == 1) ? kbuf : vbuf);
        const float sc = (type == 0) ? 0.125f : 1.f;
#pragma unroll
        for (int i = 0; i < 4; ++i) {
          const int row = row0 + i;
          const int b_ = row / S_TOT;
          const int s_ = row - b_ * S_TOT;
          dst[(((size_t)(b_ * NHEAD + head)) * S_TOT + s_) * CH + chn] = (acc[m][n][i] + bv) * sc;
        }
      }
    }
  }
}

// ---------------- attention helpers ----------------
__device__ __forceinline__ float dot64(const float4* __restrict__ q, const float* __restrict__ kp) {
  const float4* k4 = (const float4*)kp;
  float s = 0.f;
#pragma unroll
  for (int i = 0; i < 16; ++i) {
    float4 a = q[i]; float4 b = k4[i];
    s = fmaf(a.x, b.x, s); s = fmaf(a.y, b.y, s);
    s = fmaf(a.z, b.z, s); s = fmaf(a.w, b.w, s);
  }
  return s;
}

__device__ __forceinline__ void fma64(float4* __restrict__ acc, float w, const float* __restrict__ vp) {
  const float4* v4 = (const float4*)vp;
#pragma unroll
  for (int i = 0; i < 16; ++i) {
    float4 v = v4[i];
    acc[i].x = fmaf(w, v.x, acc[i].x);
    acc[i].y = fmaf(w, v.y, acc[i].y);
    acc[i].z = fmaf(w, v.z, acc[i].z);
    acc[i].w = fmaf(w, v.w, acc[i].w);
  }
}

__device__ __forceinline__ void store_ctx_bf16(short* ctx, size_t base, const float4* acc) {
  unsigned int* cp = (unsigned int*)(ctx + base);
#pragma unroll
  for (int i = 0; i < 16; ++i) {
    cp[2 * i]     = f2bf(acc[i].x) | (f2bf(acc[i].y) << 16);
    cp[2 * i + 1] = f2bf(acc[i].z) | (f2bf(acc[i].w) << 16);
  }
}

// ---------------- attention: text queries (s in [0,64)) ----------------
__global__ __launch_bounds__(64) void attn_text(
    const float* __restrict__ qb, const float* __restrict__ kb, const float* __restrict__ vb,
    const float* __restrict__ mask, short* __restrict__ ctx)
{
  __shared__ float smem[64][65];
  const int bh = blockIdx.x;
  const int b_ = bh >> 4, head = bh & 15;
  const int tq = threadIdx.x;

  float4 q[16];
  const float4* qp = (const float4*)(qb + ((size_t)bh * S_TOT + tq) * CH);
#pragma unroll
  for (int i = 0; i < 16; ++i) q[i] = qp[i];

  float* sc = smem[tq];
  const float* mrow = mask + ((size_t)b_ * S_TOT + tq) * T_TXT;
  const float* kt = kb + (size_t)bh * S_TOT * CH;
  float mx = -1e30f;
  for (int j = 0; j < T_TXT; ++j) {
    float d = dot64(q, kt + j * CH);
    float m = mrow[j];
    d = d * m - 10000.f * (1.f - m);
    sc[j] = d; mx = fmaxf(mx, d);
  }
  float l = 0.f;
  for (int j = 0; j < T_TXT; ++j) { float e = __expf(sc[j] - mx); sc[j] = e; l += e; }
  const float inv = 1.f / l;

  float4 acc[16];
#pragma unroll
  for (int i = 0; i < 16; ++i) acc[i] = make_float4(0.f, 0.f, 0.f, 0.f);
  const float* vt = vb + (size_t)bh * S_TOT * CH;
  for (int j = 0; j < T_TXT; ++j) fma64(acc, sc[j] * inv, vt + j * CH);

  store_ctx_bf16(ctx, ((size_t)(b_ * S_TOT + tq)) * HID + head * CH, acc);
}

// ---------------- attention: image0 queries (32x32, 9x9 causal) ----------------
__global__ __launch_bounds__(64) void attn_img0(
    const float* __restrict__ qb, const float* __restrict__ kb, const float* __restrict__ vb,
    const float* __restrict__ mask, short* __restrict__ ctx)
{
  __shared__ float smem[64][109];
  const int bid = blockIdx.x;
  const int bh = bid >> 4;
  const int p = (bid & 15) * 64 + threadIdx.x;
  const int qi = p >> 5, qj = p & 31;
  const int s = OFF0 + p;
  const int b_ = bh >> 4, head = bh & 15;

  float4 q[16];
  const float4* qp = (const float4*)(qb + ((size_t)bh * S_TOT + s) * CH);
#pragma unroll
  for (int i = 0; i < 16; ++i) q[i] = qp[i];

  float* sc = smem[threadIdx.x];
  const float* mrow = mask + ((size_t)b_ * S_TOT + s) * T_TXT;
  const float* kt = kb + (size_t)bh * S_TOT * CH;
  float mx = -1e30f;
  for (int j = 0; j < T_TXT; ++j) {
    float d = dot64(q, kt + j * CH);
    float m = mrow[j];
    d = d * m - 10000.f * (1.f - m);
    sc[j] = d; mx = fmaxf(mx, d);
  }
  const float* k0 = kb + ((size_t)bh * S_TOT + OFF0) * CH;
  for (int o = 0; o < 41; ++o) {
    const int di = o / 9 - 4, dj = o % 9 - 4;
    const int ki = qi + di, kj = qj + dj;
    float d = 0.f;
    if ((unsigned)ki < 32u && (unsigned)kj < 32u)
      d = dot64(q, k0 + (ki * 32 + kj) * CH);
    sc[64 + o] = d; mx = fmaxf(mx, d);
  }
  float l = 0.f;
  for (int j = 0; j < 105; ++j) { float e = __expf(sc[j] - mx); sc[j] = e; l += e; }
  const float inv = 1.f / l;

  float4 acc[16];
#pragma unroll
  for (int i = 0; i < 16; ++i) acc[i] = make_float4(0.f, 0.f, 0.f, 0.f);
  const float* vt = vb + (size_t)bh * S_TOT * CH;
  for (int j = 0; j < T_TXT; ++j) fma64(acc, sc[j] * inv, vt + j * CH);
  const float* v0 = vb + ((size_t)bh * S_TOT + OFF0) * CH;
  for (int o = 0; o < 41; ++o) {
    const int di = o / 9 - 4, dj = o % 9 - 4;
    const int ki = qi + di, kj = qj + dj;
    if ((unsigned)ki < 32u && (unsigned)kj < 32u)
      fma64(acc, sc[64 + o] * inv, v0 + (ki * 32 + kj) * CH);
  }
  store_ctx_bf16(ctx, ((size_t)(b_ * S_TOT + s)) * HID + head * CH, acc);
}

// ---------------- attention: image1 queries (64x64; 7x7 over k0 + 9x9 causal over k1) ----------------
__global__ __launch_bounds__(64) void attn_img1(
    const float* __restrict__ qb, const float* __restrict__ kb, const float* __restrict__ vb,
    const float* __restrict__ mask, short* __restrict__ ctx)
{
  __shared__ float smem[64][157];
  const int bid = blockIdx.x;
  const int bh = bid >> 6;
  const int p = (bid & 63) * 64 + threadIdx.x;
  const int qi = p >> 6, qj = p & 63;
  const int s = OFF1 + p;
  const int b_ = bh >> 4, head = bh & 15;

  float4 q[16];
  const float4* qp = (const float4*)(qb + ((size_t)bh * S_TOT + s) * CH);
#pragma unroll
  for (int i = 0; i < 16; ++i) q[i] = qp[i];

  float* sc = smem[threadIdx.x];
  const float* mrow = mask + ((size_t)b_ * S_TOT + s) * T_TXT;
  const float* kt = kb + (size_t)bh * S_TOT * CH;
  float mx = -1e30f;
  for (int j = 0; j < T_TXT; ++j) {
    float d = dot64(q, kt + j * CH);
    float m = mrow[j];
    d = d * m - 10000.f * (1.f - m);
    sc[j] = d; mx = fmaxf(mx, d);
  }
  const float* k0 = kb + ((size_t)bh * S_TOT + OFF0) * CH;
  const int ki0 = qi >> 1, kj0 = qj >> 1;
  for (int o = 0; o < 49; ++o) {
    const int ki = ki0 + o / 7 - 3, kj = kj0 + o % 7 - 3;
    float d = 0.f;
    if ((unsigned)ki < 32u && (unsigned)kj < 32u)
      d = dot64(q, k0 + (ki * 32 + kj) * CH);
    sc[64 + o] = d; mx = fmaxf(mx, d);
  }
  const float* k1 = kb + ((size_t)bh * S_TOT + OFF1) * CH;
  for (int o = 0; o < 41; ++o) {
    const int ki = qi + o / 9 - 4, kj = qj + o % 9 - 4;
    float d = 0.f;
    if ((unsigned)ki < 64u && (unsigned)kj < 64u)
      d = dot64(q, k1 + (ki * 64 + kj) * CH);
    sc[113 + o] = d; mx = fmaxf(mx, d);
  }
  float l = 0.f;
  for (int j = 0; j < 154; ++j) { float e = __expf(sc[j] - mx); sc[j] = e; l += e; }
  const float inv = 1.f / l;

  float4 acc[16];
#pragma unroll
  for (int i = 0; i < 16; ++i) acc[i] = make_float4(0.f, 0.f, 0.f, 0.f);
  const float* vt = vb + (size_t)bh * S_TOT * CH;
  for (int j = 0; j < T_TXT; ++j) fma64(acc, sc[j] * inv, vt + j * CH);
  const float* v0 = vb + ((size_t)bh * S_TOT + OFF0) * CH;
  for (int o = 0; o < 49; ++o) {
    const int ki = ki0 + o / 7 - 3, kj = kj0 + o % 7 - 3;
    if ((unsigned)ki < 32u && (unsigned)kj < 32u)
      fma64(acc, sc[64 + o] * inv, v0 + (ki * 32 + kj) * CH);
  }
  const float* v1 = vb + ((size_t)bh * S_TOT + OFF1) * CH;
  for (int o = 0; o < 41; ++o) {
    const int ki = qi + o / 9 - 4, kj = qj + o % 9 - 4;
    if ((unsigned)ki < 64u && (unsigned)kj < 64u)
      fma64(acc, sc[113 + o] * inv, v1 + (ki * 64 + kj) * CH);
  }
  store_ctx_bf16(ctx, ((size_t)(b_ * S_TOT + s)) * HID + head * CH, acc);
}

// ---------------- launch ----------------
extern "C" void kernel_launch(void* const* d_in, const int* in_sizes, int n_in,
                              void* d_out, int out_size, void* d_ws, size_t ws_size,
                              hipStream_t stream) {
  const float* hidden = (const float*)d_in[0];
  const float* mask   = (const float*)d_in[1];
  const float* w_qkv  = (const float*)d_in[2];
  const float* b_qkv  = (const float*)d_in[3];
  const float* w_out  = (const float*)d_in[4];
  const float* b_out  = (const float*)d_in[5];
  float* out = (float*)d_out;

  const size_t NB = (size_t)BN_TOT * S_TOT * CH;   // 21,233,664 elements
  float* qbuf = (float*)d_ws;
  float* kbuf = qbuf + NB;
  float* vbuf = kbuf + NB;
  short* hbf   = (short*)(vbuf + NB);   // hidden bf16; later ALIASED as ctx bf16
  short* wqkvT = hbf + NB;              // [3072][1024] bf16
  short* woutT = wqkvT + (size_t)3072 * 1024;  // [1024][1024] bf16

  const int M = BATCH * S_TOT;   // 20736

  // 0) conversions
  cvt_bf16<<<(int)((NB / 8 + 255) / 256), 256, 0, stream>>>(hidden, (unsigned int*)hbf, (int)(NB / 8));
  cvt_T<<<dim3(3072 / 32, 1024 / 32), dim3(32, 8), 0, stream>>>(w_qkv, wqkvT, 1024, 3072);
  cvt_T<<<dim3(1024 / 32, 1024 / 32), dim3(32, 8), 0, stream>>>(w_out, woutT, 1024, 1024);

  // 1) QKV projection (bf16 MFMA) with q/k/v scatter epilogue
  gemm_mfma<1><<<dim3(M / 128, 3072 / 128), 256, 0, stream>>>(
      hbf, wqkvT, b_qkv, nullptr, qbuf, kbuf, vbuf, M, 3072, 1024);

  // 2) attention (f32 math, bf16 ctx output; ctx aliases hbf — hidden_bf16 already consumed)
  short* ctx = hbf;
  attn_text<<<BN_TOT, 64, 0, stream>>>(qbuf, kbuf, vbuf, mask, ctx);
  attn_img0<<<BN_TOT * 16, 64, 0, stream>>>(qbuf, kbuf, vbuf, mask, ctx);
  attn_img1<<<BN_TOT * 64, 64, 0, stream>>>(qbuf, kbuf, vbuf, mask, ctx);

  // 3) output projection (bf16 MFMA)
  gemm_mfma<0><<<dim3(M / 128, 1024 / 128), 256, 0, stream>>>(
      ctx, woutT, b_out, out, nullptr, nullptr, nullptr, M, 1024, 1024);
}